// Round 17
// baseline (105.033 us; speedup 1.0000x reference)
//
#include <hip/hip_runtime.h>
#include <math.h>

// CandidateAwareClock — R13 (5th submit; rounds 13-16 were broker timeouts,
// kernel never ran): single-pass online-softmax, TWO WAVES PER ROW.
//   q = emb[cand[b]]; k_l = emb[items[b,l]]
//   logits_l = dot(k_l,q) * gate[dts[b,l]] / tau   (gate row 0 == 0)
//   masked softmax -> attn; u = sum_l attn_l * k_l; tau = softplus(raw)+1e-6
// Outputs concatenated: u [B*64], attn [B*200], tau [1]
//
// R12's ILP axis (widen+prefetch) was neutral -> reverted to R9 loop body.
// R13 tests the TLP axis: each row's compacted entries split across 2 waves
// (~2x fewer serialized gather groups per wave; 8192 waves grid-wide).
// Cross-wave combine of (m, s, acc) via LDS + one __syncthreads:
//   mf = max(mA,mB); sf = sA*e^{mA-mf} + sB*e^{mB-mf}; u likewise; attn from
//   stored logits with final (mf, sf) -> same math as reference softmax.

constexpr int Bsz  = 4096;
constexpr int Lseq = 200;
constexpr int Dim  = 64;
constexpr int RPB  = 2;     // rows per block (2 waves per row)

__global__ __launch_bounds__(256, 4)
void cac_kernel(const int* __restrict__ items,
                const int* __restrict__ dts,
                const int* __restrict__ mask,
                const int* __restrict__ cand,
                const float* __restrict__ emb,
                const float* __restrict__ gate,
                const float* __restrict__ rawtau,
                float* __restrict__ out_u,
                float* __restrict__ out_attn,
                float* __restrict__ out_tau)
{
    __shared__ int   cpos[RPB][Lseq];    // compacted -> original position
    __shared__ int   crow[RPB][Lseq];    // compacted -> item row
    __shared__ float cgate[RPB][Lseq];   // compacted -> gate value
    __shared__ float clog[RPB][Lseq];    // compacted -> logit
    __shared__ int   cnt_lds[RPB];
    __shared__ float pu[RPB][2][Dim];    // per-half unnormalized u partials
    __shared__ float pm[RPB][2];         // per-half running max
    __shared__ float ps[RPB][2];         // per-half denom partial

    const int tid  = threadIdx.x;
    const int wv   = tid >> 6;
    const int lane = tid & 63;
    const int slot = wv >> 1;            // row slot within block (0..1)
    const int half = wv & 1;             // which half of the entries
    const int b    = blockIdx.x * RPB + slot;

    // tau
    const float raw = rawtau[0];
    const float sp  = (raw > 20.f) ? raw : log1pf(expf(raw));
    const float tau = sp + 1e-6f;
    const float inv_tau = 1.0f / tau;
    if (blockIdx.x == 0 && tid == 0) out_tau[0] = tau;

    // q fragment: lane (r,j) holds q dims {16i+4j..+3}
    const int r = lane >> 2;
    const int j = lane & 3;
    const float4* qrow = (const float4*)(emb + (size_t)cand[b] * Dim);
    float4 qv[4];
    #pragma unroll
    for (int i = 0; i < 4; ++i) qv[i] = qrow[i * 4 + j];

    // masked-zero attn writes: wave half owns chunks {2*half, 2*half+1}
    int mz[2];
    #pragma unroll
    for (int k = 0; k < 2; ++k) {
        const int p = (2 * half + k) * 64 + lane;
        mz[k] = (p < Lseq) ? mask[(size_t)b * Lseq + p] : 1;
    }

    // ---- compaction: only half==0 builds the lists (full row) ----
    if (half == 0) {
        int rowk[4], mk[4];
        float gk[4];
        #pragma unroll
        for (int k = 0; k < 4; ++k) {
            const int  p  = k * 64 + lane;
            const bool in = (p < Lseq);
            rowk[k] = in ? items[(size_t)b * Lseq + p] : 0;
            mk[k]   = in ? mask[(size_t)b * Lseq + p] : 0;
            const int dt = in ? dts[(size_t)b * Lseq + p] : 0;
            gk[k] = (dt == 0) ? 0.f : gate[dt];      // padding_idx=0
        }
        unsigned long long bals[4];
        int offs[5];
        offs[0] = 0;
        #pragma unroll
        for (int k = 0; k < 4; ++k) {
            bals[k] = __ballot(mk[k] != 0);
            offs[k + 1] = offs[k] + __popcll(bals[k]);
        }
        const unsigned long long ltmask = (1ull << lane) - 1ull;
        #pragma unroll
        for (int k = 0; k < 4; ++k) {
            if (mk[k]) {
                const int idx = offs[k] + __popcll(bals[k] & ltmask);
                cpos[slot][idx]  = k * 64 + lane;
                crow[slot][idx]  = rowk[k];
                cgate[slot][idx] = gk[k];
            }
        }
        if (lane == 0) cnt_lds[slot] = offs[4];
    }
    __syncthreads();

    const int cnt = cnt_lds[slot];                   // >=1 (mask[:,0]=True)
    const int h   = (cnt + 1) >> 1;
    const int elo = half ? h : 0;
    const int ehi = half ? cnt : h;

    // ---- flash loop over my half of the compacted entries ----
    float acc[16];
    #pragma unroll
    for (int i = 0; i < 16; ++i) acc[i] = 0.f;
    float m = -INFINITY, s_l = 0.f;

    for (int g = elo; g < ehi; g += 16) {
        const int  e     = g + r;
        const bool valid = (e < ehi);
        const int  ec    = valid ? e : (ehi - 1);
        const int  row   = crow[slot][ec];           // 4-lane same-addr broadcast
        const float cg   = cgate[slot][ec];
        const float4* kp = (const float4*)(emb + (size_t)row * Dim);
        float4 kv[4];
        #pragma unroll
        for (int i = 0; i < 4; ++i) kv[i] = kp[i * 4 + j];   // lane's 64B line

        float p = 0.f;
        #pragma unroll
        for (int i = 0; i < 4; ++i) {
            p = fmaf(kv[i].x, qv[i].x, p);
            p = fmaf(kv[i].y, qv[i].y, p);
            p = fmaf(kv[i].z, qv[i].z, p);
            p = fmaf(kv[i].w, qv[i].w, p);
        }
        p += __shfl_xor(p, 1, 64);
        p += __shfl_xor(p, 2, 64);

        const float logit = p * cg * inv_tau;
        const float leff  = valid ? logit : -INFINITY;

        float gm = leff;
        #pragma unroll
        for (int off = 4; off < 64; off <<= 1)
            gm = fmaxf(gm, __shfl_xor(gm, off, 64));

        if (gm > m) {                                // wave-uniform
            const float scale = __expf(m - gm);
            s_l *= scale;
            #pragma unroll
            for (int i = 0; i < 16; ++i) acc[i] *= scale;
            m = gm;
        }

        const float wgt = __expf(leff - m);          // invalid -> 0
        if (valid && j == 0) clog[slot][e] = logit;
        if (j == 0) s_l += wgt;
        #pragma unroll
        for (int i = 0; i < 4; ++i) {
            acc[4 * i + 0] = fmaf(wgt, kv[i].x, acc[4 * i + 0]);
            acc[4 * i + 1] = fmaf(wgt, kv[i].y, acc[4 * i + 1]);
            acc[4 * i + 2] = fmaf(wgt, kv[i].z, acc[4 * i + 2]);
            acc[4 * i + 3] = fmaf(wgt, kv[i].w, acc[4 * i + 3]);
        }
    }

    // ---- in-wave reduce; publish partials ----
    #pragma unroll
    for (int off = 4; off < 64; off <<= 1) {
        #pragma unroll
        for (int i = 0; i < 16; ++i) acc[i] += __shfl_xor(acc[i], off, 64);
    }
    float s = s_l;                                   // nonzero only at j==0 lanes
    #pragma unroll
    for (int off = 1; off < 64; off <<= 1) s += __shfl_xor(s, off, 64);

    if (r == 0) {                                    // lanes 0..3 (j=lane)
        #pragma unroll
        for (int i = 0; i < 4; ++i) {
            float4 o;
            o.x = acc[4 * i + 0]; o.y = acc[4 * i + 1];
            o.z = acc[4 * i + 2]; o.w = acc[4 * i + 3];
            *(float4*)&pu[slot][half][i * 16 + 4 * j] = o;   // dims 16i+4j..+3
        }
    }
    if (lane == 0) { pm[slot][half] = m; ps[slot][half] = s; }
    __syncthreads();

    // ---- combine the two halves (lane-redundant, cheap) ----
    const float mA = pm[slot][0], mB = pm[slot][1];
    const float mf = fmaxf(mA, mB);
    const float cA = __expf(mA - mf), cB = __expf(mB - mf);
    const float sf = ps[slot][0] * cA + ps[slot][1] * cB;
    const float inv_sf = 1.0f / sf;

    if (half == 0)                                   // coalesced 64-float u write
        out_u[(size_t)b * Dim + lane] =
            (pu[slot][0][lane] * cA + pu[slot][1][lane] * cB) * inv_sf;

    // attn: zeros for my chunks; values for my compacted entries
    #pragma unroll
    for (int k = 0; k < 2; ++k) {
        const int p = (2 * half + k) * 64 + lane;
        if (p < Lseq && !mz[k]) out_attn[(size_t)b * Lseq + p] = 0.f;
    }
    for (int e = elo + lane; e < ehi; e += 64) {
        const float a = __expf(clog[slot][e] - mf) * inv_sf;
        out_attn[(size_t)b * Lseq + cpos[slot][e]] = a;
    }
}

extern "C" void kernel_launch(void* const* d_in, const int* in_sizes, int n_in,
                              void* d_out, int out_size, void* d_ws, size_t ws_size,
                              hipStream_t stream) {
    const int*   items  = (const int*)  d_in[0];  // [B,L]
    const int*   dts    = (const int*)  d_in[1];  // [B,L]
    const int*   mask   = (const int*)  d_in[2];  // [B,L]
    const int*   cand   = (const int*)  d_in[3];  // [B]
    const float* emb    = (const float*)d_in[4];  // [VOCAB,64]
    const float* gate   = (const float*)d_in[5];  // [128,1]
    const float* rawtau = (const float*)d_in[6];  // [1]

    float* out_u    = (float*)d_out;                       // B*64
    float* out_attn = out_u + Bsz * Dim;                   // B*200
    float* out_tau  = out_attn + Bsz * Lseq;               // 1

    cac_kernel<<<Bsz / RPB, 256, 0, stream>>>(items, dts, mask, cand, emb, gate,
                                              rawtau, out_u, out_attn, out_tau);
}